// Round 13
// baseline (679.887 us; speedup 1.0000x reference)
//
#include <hip/hip_runtime.h>
#include <hip/hip_bf16.h>
#include <stdint.h>

#define NTOK 4096
#define DIM  1024
#define TOPK 128
#define GB   64      // greedy blocks, single-wave each
#define GT   64      // threads per greedy block; GB*GT == NTOK
#define NEGM -1e30f

typedef __attribute__((ext_vector_type(8))) short bf16x8;
typedef __attribute__((ext_vector_type(4))) float f32x4;

// ---------------------------------------------------------------------------
// k_prep: rel[n] = ((-a[n]) - min(-a) + 1e-6) / (max(-a) - min(-a))
// ---------------------------------------------------------------------------
__global__ __launch_bounds__(1024) void k_prep(const float* __restrict__ attn,
                                               float* __restrict__ rel) {
  __shared__ float smx[16], smn[16];
  int tid = threadIdx.x;
  float mx = -3.4e38f, mn = 3.4e38f;
  for (int n = tid; n < NTOK; n += 1024) {
    float a = attn[n];
    mx = fmaxf(mx, a); mn = fminf(mn, a);
  }
  for (int o = 32; o >= 1; o >>= 1) {
    mx = fmaxf(mx, __shfl_down(mx, o, 64));
    mn = fminf(mn, __shfl_down(mn, o, 64));
  }
  if ((tid & 63) == 0) { smx[tid >> 6] = mx; smn[tid >> 6] = mn; }
  __syncthreads();
  if (tid == 0) {
    float MX = smx[0], MN = smn[0];
    for (int w = 1; w < 16; ++w) { MX = fmaxf(MX, smx[w]); MN = fminf(MN, smn[w]); }
    smx[0] = MX; smn[0] = MN;
  }
  __syncthreads();
  float amax = smx[0], amin = smn[0];
  float rmin  = -amax;
  float range = (-amin) - rmin;
  for (int n = tid; n < NTOK; n += 1024) {
    float r = -attn[n];
    rel[n] = ((r - rmin) + 1e-6f) / range;
  }
}

// ---------------------------------------------------------------------------
// k_norm: xn = x/||x||, then EXACT bf16 split: hi=bf16(xn), lo=bf16(xn-hi).
// ---------------------------------------------------------------------------
__global__ __launch_bounds__(256) void k_norm(const float* __restrict__ x,
                                              __hip_bfloat16* __restrict__ H,
                                              __hip_bfloat16* __restrict__ L) {
  __shared__ float ps[4];
  int row = blockIdx.x, tid = threadIdx.x;
  const float4* xr = (const float4*)(x + (size_t)row * DIM);
  float4 v = xr[tid];
  float s = v.x * v.x + v.y * v.y + v.z * v.z + v.w * v.w;
  for (int o = 32; o >= 1; o >>= 1) s += __shfl_down(s, o, 64);
  if ((tid & 63) == 0) ps[tid >> 6] = s;
  __syncthreads();
  if (tid == 0) ps[0] = ps[0] + ps[1] + ps[2] + ps[3];
  __syncthreads();
  float nrm = sqrtf(ps[0]);
  float xf[4] = {v.x / nrm, v.y / nrm, v.z / nrm, v.w / nrm};
  __hip_bfloat16 hh[4], ll[4];
#pragma unroll
  for (int e = 0; e < 4; ++e) {
    hh[e] = __float2bfloat16(xf[e]);
    float lof = xf[e] - __bfloat162float(hh[e]);
    ll[e] = __float2bfloat16(lof);
  }
  *(short4*)(H + (size_t)row * DIM + tid * 4) = *(short4*)hh;
  *(short4*)(L + (size_t)row * DIM + tid * 4) = *(short4*)ll;
}

// ---------------------------------------------------------------------------
// k_gemm (MFMA split-bf16): UNCHANGED from r12 (ker bitwise stable).
// ---------------------------------------------------------------------------
#define GBK 64
__global__ __launch_bounds__(256) void k_gemm(const __hip_bfloat16* __restrict__ H,
                                              const __hip_bfloat16* __restrict__ L,
                                              const float* __restrict__ rel,
                                              float* __restrict__ ker) {
  int bi = blockIdx.y, bj = blockIdx.x;
  if (bi > bj) return;
  __shared__ __align__(16) char smem[36864];
  int tid = threadIdx.x;
  int lane = tid & 63, wid = tid >> 6;
  int wr = wid >> 1, wc = wid & 1;
  int lm = lane & 15, quad = lane >> 4;
  const __hip_bfloat16* PA[4] = {H, H, L, L};
  const __hip_bfloat16* PB[4] = {H, L, H, L};
  int srow = wid * 32 + (lane >> 3);
  int kcs  = (lane & 7) ^ ((lane >> 3) & 7);
  f32x4 acc[4][4];
#pragma unroll
  for (int r = 0; r < 4; ++r)
#pragma unroll
    for (int c = 0; c < 4; ++c) acc[r][c] = (f32x4){0.f, 0.f, 0.f, 0.f};

  for (int kt = 0; kt < 4096; kt += GBK) {
    int p = kt >> 10, kk = kt & 1023;
    const __hip_bfloat16* Ab = PA[p] + (size_t)(bi * 128) * DIM + kk;
    const __hip_bfloat16* Bb = PB[p] + (size_t)(bj * 128) * DIM + kk;
    __syncthreads();
#pragma unroll
    for (int q = 0; q < 4; ++q) {
      const __hip_bfloat16* ga = Ab + (size_t)(srow + q * 8) * DIM + kcs * 8;
      const __hip_bfloat16* gb = Bb + (size_t)(srow + q * 8) * DIM + kcs * 8;
      __builtin_amdgcn_global_load_lds(
          (const __attribute__((address_space(1))) void*)ga,
          (__attribute__((address_space(3))) void*)(smem + (wid * 4 + q) * 1024),
          16, 0, 0);
      __builtin_amdgcn_global_load_lds(
          (const __attribute__((address_space(1))) void*)gb,
          (__attribute__((address_space(3))) void*)(smem + 16384 +
                                                    (wid * 4 + q) * 1024),
          16, 0, 0);
    }
    __syncthreads();
#pragma unroll
    for (int kq = 0; kq < 2; ++kq) {
      int kc = kq * 4 + quad;
      bf16x8 af[4], bff[4];
#pragma unroll
      for (int r = 0; r < 4; ++r) {
        int row = wr * 64 + r * 16 + lm;
        af[r] = *(const bf16x8*)(smem + row * 128 + ((kc ^ (lm & 7)) * 16));
      }
#pragma unroll
      for (int c = 0; c < 4; ++c) {
        int row = wc * 64 + c * 16 + lm;
        bff[c] = *(const bf16x8*)(smem + 16384 + row * 128 +
                                  ((kc ^ (lm & 7)) * 16));
      }
#pragma unroll
      for (int r = 0; r < 4; ++r)
#pragma unroll
        for (int c = 0; c < 4; ++c)
          acc[r][c] = __builtin_amdgcn_mfma_f32_16x16x32_bf16(
              af[r], bff[c], acc[r][c], 0, 0, 0);
    }
  }
  float rr[16], rc[4];
#pragma unroll
  for (int r = 0; r < 4; ++r)
#pragma unroll
    for (int e = 0; e < 4; ++e)
      rr[r * 4 + e] = rel[bi * 128 + wr * 64 + r * 16 + quad * 4 + e];
#pragma unroll
  for (int c = 0; c < 4; ++c) rc[c] = rel[bj * 128 + wc * 64 + c * 16 + lm];
#pragma unroll
  for (int r = 0; r < 4; ++r) {
    int grow = bi * 128 + wr * 64 + r * 16 + quad * 4;
#pragma unroll
    for (int c = 0; c < 4; ++c) {
      int gcol = bj * 128 + wc * 64 + c * 16 + lm;
#pragma unroll
      for (int e = 0; e < 4; ++e)
        ker[(size_t)(grow + e) * NTOK + gcol] =
            (acc[r][c][e] * rr[r * 4 + e]) * rc[c];
    }
  }
  if (bi != bj) {
    __syncthreads();
    float* Tw = (float*)(smem + wid * 4672);
#pragma unroll
    for (int c = 0; c < 4; ++c) {
#pragma unroll
      for (int r = 0; r < 4; ++r)
#pragma unroll
        for (int e = 0; e < 4; ++e)
          Tw[lm * 73 + r * 16 + quad * 4 + e] =
              (acc[r][c][e] * rc[c]) * rr[r * 4 + e];
      __syncthreads();
      int cc2 = lane >> 2, seg = lane & 3;
      float* dst = &ker[(size_t)(bj * 128 + wc * 64 + c * 16 + cc2) * NTOK +
                        bi * 128 + wr * 64 + seg * 16];
#pragma unroll
      for (int e = 0; e < 4; ++e)
        *(float4*)&dst[e * 4] = *(const float4*)&Tw[cc2 * 73 + seg * 16 + e * 4];
      __syncthreads();
    }
  }
}

// ---------------------------------------------------------------------------
// k_greedy: 64 blocks x 64 threads — SINGLE-WAVE blocks. No LDS argmax hop,
// no cross-wave publishing; __syncthreads degenerates to waitcnt (s_barrier
// trivial for 1 wave). vmcnt is per-wave, so the wave's cisT store drains at
// the compiler-inserted wait before lane0's release — no barrier needed for
// cross-lane store ordering. Exchange: 64 padded slots, polled 1-per-lane,
// winner via 6 shuffles. colbuf (64xb64) + kj issued back-to-back, drain at
// one point, proj runs on LDS after. histT[64][132]: b128, conflict-free.
// ---------------------------------------------------------------------------
__global__ __launch_bounds__(GT) void k_greedy(const float* __restrict__ ker,
                                               const float* __restrict__ feat,
                                               float* __restrict__ out,
                                               float* __restrict__ cisT,
                                               unsigned long long* __restrict__ slots) {
  __shared__ __align__(16) float histT[GT][132];   // 33.8 KB
  __shared__ __align__(16) float colbuf[TOPK];
  __shared__ int selj[TOPK];
  int tid = threadIdx.x;                        // == lane (single wave)
  int blk = blockIdx.x;
  int n = blk * GT + tid;
  float di2s = ker[(size_t)n * NTOK + n];
#pragma unroll
  for (int t = 0; t < TOPK; t += 4)
    *(float4*)&histT[tid][t] = (float4){0.f, 0.f, 0.f, 0.f};

  for (int i = 0; i < TOPK; ++i) {
    // ---- wave argmax (monotonic key, first-index tie-break), 6 shuffles
    unsigned u = __float_as_uint(di2s);
    unsigned key = (u & 0x80000000u) ? ~u : (u | 0x80000000u);
    unsigned long long pk =
        ((unsigned long long)key << 32) | (unsigned)(NTOK - 1 - n);
    for (int o = 32; o >= 1; o >>= 1) {
      unsigned long long q = __shfl_down(pk, o, 64);
      if (q > pk) pk = q;
    }
    if (tid == 0)   // release: publishes this wave's iter-(i-1) cisT store
      __hip_atomic_store(&slots[((size_t)i * GB + blk) * 8], pk,
                         __ATOMIC_RELEASE, __HIP_MEMORY_SCOPE_AGENT);
    // ---- poll: lane g polls slot g (64 slots, 64B-padded)
    unsigned long long v;
    do {
      v = __hip_atomic_load(&slots[((size_t)i * GB + tid) * 8],
                            __ATOMIC_RELAXED, __HIP_MEMORY_SCOPE_AGENT);
    } while (v == 0);
    unsigned long long b1 = v;
    for (int o = 32; o >= 1; o >>= 1) {
      unsigned long long q = __shfl_down(b1, o, 64);
      if (q > b1) b1 = q;
    }
    b1 = __shfl(b1, 0, 64);
    __builtin_amdgcn_fence(__ATOMIC_ACQUIRE, "agent");  // order cisT/ker reads
    int j = NTOK - 1 - (int)(b1 & 0xffffffffu);
    unsigned kw = (unsigned)(b1 >> 32);
    unsigned du = (kw & 0x80000000u) ? (kw & 0x7fffffffu) : ~kw;
    float sd = sqrtf(__uint_as_float(du));
    if (tid == 0) selj[i] = j;
    // ---- winner column (64 lanes x b64) + kj, overlapped RTs
    unsigned long long cu = __hip_atomic_load(
        (const unsigned long long*)(cisT + (size_t)j * TOPK) + tid,
        __ATOMIC_RELAXED, __HIP_MEMORY_SCOPE_AGENT);
    float kj = ker[(size_t)j * NTOK + n];       // 256B/block, coalesced
    union { unsigned long long u64; float f[2]; } cc; cc.u64 = cu;
    colbuf[tid * 2]     = cc.f[0];
    colbuf[tid * 2 + 1] = cc.f[1];
    __syncthreads();   // single-wave: waitcnt only; colbuf visible wave-wide
    float proj = 0.f;
    for (int t = 0; t < i; t += 4) {
      float4 c4 = *(const float4*)&colbuf[t];
      float4 h4 = *(const float4*)&histT[tid][t];
      proj += c4.x * h4.x + c4.y * h4.y + c4.z * h4.z + c4.w * h4.w;
    }
    float eis = (kj - proj) / sd;
    __hip_atomic_store(&cisT[(size_t)n * TOPK + i], eis, __ATOMIC_RELAXED,
                       __HIP_MEMORY_SCOPE_AGENT);
    histT[tid][i] = eis;
    di2s -= eis * eis;
    if (n == j) di2s = NEGM;
  }
  __syncthreads();
  // ---- gather output rows: block b copies rows k = b, b+GB
  for (int k = blk; k < TOPK; k += GB) {
    int j = selj[k];
    const float4* src = (const float4*)(feat + (size_t)j * DIM);
    float4* dst = (float4*)(out + (size_t)k * DIM);
#pragma unroll
    for (int e = 0; e < 4; ++e) dst[tid + e * GT] = src[tid + e * GT];
  }
}

// ---------------------------------------------------------------------------
// ws layout (bytes):
//   [0,524288)        slots: 128 iters x 64 blocks x 64B (zeroed each launch)
//   [524288,540672)   rel  : 4096 f32
//   [1MB, +8MB)       H    : 4096x1024 bf16
//   [1MB+8MB, +8MB)   L    : 4096x1024 bf16
//   [1MB+16MB, +2MB)  cisT : 4096x128 f32
//   [1MB+20MB, +64MB) ker  : 4096x4096 f32
// total ~85 MB
// ---------------------------------------------------------------------------
extern "C" void kernel_launch(void* const* d_in, const int* in_sizes, int n_in,
                              void* d_out, int out_size, void* d_ws, size_t ws_size,
                              hipStream_t stream) {
  const float* feat = (const float*)d_in[0];
  const float* attn = (const float*)d_in[1];
  float* out = (float*)d_out;
  char* ws = (char*)d_ws;

  unsigned long long* slots = (unsigned long long*)ws;
  float* rel = (float*)(ws + 524288);
  __hip_bfloat16* H = (__hip_bfloat16*)(ws + (1 << 20));
  __hip_bfloat16* L = (__hip_bfloat16*)(ws + (1 << 20) + (8 << 20));
  float* cisT = (float*)(ws + (1 << 20) + (16 << 20));
  float* ker  = (float*)(ws + (1 << 20) + (16 << 20) + (4 << 20));

  hipMemsetAsync(d_ws, 0, 524288, stream);
  k_prep<<<1, 1024, 0, stream>>>(attn, rel);
  k_norm<<<NTOK, 256, 0, stream>>>(feat, H, L);
  k_gemm<<<dim3(32, 32), 256, 0, stream>>>(H, L, rel, ker);
  k_greedy<<<GB, GT, 0, stream>>>(ker, feat, out, cisT, slots);
}

// Round 14
// 596.692 us; speedup vs baseline: 1.1394x; 1.1394x over previous
//
#include <hip/hip_runtime.h>
#include <hip/hip_bf16.h>
#include <stdint.h>

#define NTOK 4096
#define DIM  1024
#define TOPK 128
#define GB   32      // greedy blocks (r11/r12 empirical optimum)
#define GT   128     // threads per greedy block; GB*GT == NTOK
#define NEGM -1e30f

typedef __attribute__((ext_vector_type(8))) short bf16x8;
typedef __attribute__((ext_vector_type(4))) float f32x4;

// ---------------------------------------------------------------------------
// k_prep: rel[n] = ((-a[n]) - min(-a) + 1e-6) / (max(-a) - min(-a))
// ---------------------------------------------------------------------------
__global__ __launch_bounds__(1024) void k_prep(const float* __restrict__ attn,
                                               float* __restrict__ rel) {
  __shared__ float smx[16], smn[16];
  int tid = threadIdx.x;
  float mx = -3.4e38f, mn = 3.4e38f;
  for (int n = tid; n < NTOK; n += 1024) {
    float a = attn[n];
    mx = fmaxf(mx, a); mn = fminf(mn, a);
  }
  for (int o = 32; o >= 1; o >>= 1) {
    mx = fmaxf(mx, __shfl_down(mx, o, 64));
    mn = fminf(mn, __shfl_down(mn, o, 64));
  }
  if ((tid & 63) == 0) { smx[tid >> 6] = mx; smn[tid >> 6] = mn; }
  __syncthreads();
  if (tid == 0) {
    float MX = smx[0], MN = smn[0];
    for (int w = 1; w < 16; ++w) { MX = fmaxf(MX, smx[w]); MN = fminf(MN, smn[w]); }
    smx[0] = MX; smn[0] = MN;
  }
  __syncthreads();
  float amax = smx[0], amin = smn[0];
  float rmin  = -amax;
  float range = (-amin) - rmin;
  for (int n = tid; n < NTOK; n += 1024) {
    float r = -attn[n];
    rel[n] = ((r - rmin) + 1e-6f) / range;
  }
}

// ---------------------------------------------------------------------------
// k_norm: xn = x/||x||, then EXACT bf16 split: hi=bf16(xn), lo=bf16(xn-hi).
// ---------------------------------------------------------------------------
__global__ __launch_bounds__(256) void k_norm(const float* __restrict__ x,
                                              __hip_bfloat16* __restrict__ H,
                                              __hip_bfloat16* __restrict__ L) {
  __shared__ float ps[4];
  int row = blockIdx.x, tid = threadIdx.x;
  const float4* xr = (const float4*)(x + (size_t)row * DIM);
  float4 v = xr[tid];
  float s = v.x * v.x + v.y * v.y + v.z * v.z + v.w * v.w;
  for (int o = 32; o >= 1; o >>= 1) s += __shfl_down(s, o, 64);
  if ((tid & 63) == 0) ps[tid >> 6] = s;
  __syncthreads();
  if (tid == 0) ps[0] = ps[0] + ps[1] + ps[2] + ps[3];
  __syncthreads();
  float nrm = sqrtf(ps[0]);
  float xf[4] = {v.x / nrm, v.y / nrm, v.z / nrm, v.w / nrm};
  __hip_bfloat16 hh[4], ll[4];
#pragma unroll
  for (int e = 0; e < 4; ++e) {
    hh[e] = __float2bfloat16(xf[e]);
    float lof = xf[e] - __bfloat162float(hh[e]);
    ll[e] = __float2bfloat16(lof);
  }
  *(short4*)(H + (size_t)row * DIM + tid * 4) = *(short4*)hh;
  *(short4*)(L + (size_t)row * DIM + tid * 4) = *(short4*)ll;
}

// ---------------------------------------------------------------------------
// k_gemm (MFMA split-bf16): same math/order as r10-r13 (ker bitwise equal).
// FIX vs r12: proper single-barrier ping-pong. r12 did
//   barrier; issue loads; barrier(vmcnt0!); compute   -> full RT exposed/stage.
// Now: barrier; issue s+1 -> buf(1-p); compute s from buf(p). The next
// stage's barrier drains loads that had all of compute(s) to land ->
// exposed latency ~= max(0, RT - compute). LDS: 2x32KB buffers (64KB,
// still 2 blocks/CU). XOR-swizzled chunks as in r12 (lane-linear staging,
// conflict-free b128 fragment reads).
// ---------------------------------------------------------------------------
#define GBK 64
__global__ __launch_bounds__(256) void k_gemm(const __hip_bfloat16* __restrict__ H,
                                              const __hip_bfloat16* __restrict__ L,
                                              const float* __restrict__ rel,
                                              float* __restrict__ ker) {
  int bi = blockIdx.y, bj = blockIdx.x;
  if (bi > bj) return;
  __shared__ __align__(16) char smem[65536];  // A: p*16K, B: 32K + p*16K
  int tid = threadIdx.x;
  int lane = tid & 63, wid = tid >> 6;
  int wr = wid >> 1, wc = wid & 1;
  int lm = lane & 15, quad = lane >> 4;
  const __hip_bfloat16* PA[4] = {H, H, L, L};
  const __hip_bfloat16* PB[4] = {H, L, H, L};
  int srow = wid * 32 + (lane >> 3);
  int kcs  = (lane & 7) ^ ((lane >> 3) & 7);
  f32x4 acc[4][4];
#pragma unroll
  for (int r = 0; r < 4; ++r)
#pragma unroll
    for (int c = 0; c < 4; ++c) acc[r][c] = (f32x4){0.f, 0.f, 0.f, 0.f};

  // ---- preload stage 0 into buffer 0
  {
    const __hip_bfloat16* Ab = PA[0] + (size_t)(bi * 128) * DIM;
    const __hip_bfloat16* Bb = PB[0] + (size_t)(bj * 128) * DIM;
#pragma unroll
    for (int q = 0; q < 4; ++q) {
      const __hip_bfloat16* ga = Ab + (size_t)(srow + q * 8) * DIM + kcs * 8;
      const __hip_bfloat16* gb = Bb + (size_t)(srow + q * 8) * DIM + kcs * 8;
      __builtin_amdgcn_global_load_lds(
          (const __attribute__((address_space(1))) void*)ga,
          (__attribute__((address_space(3))) void*)(smem + (wid * 4 + q) * 1024),
          16, 0, 0);
      __builtin_amdgcn_global_load_lds(
          (const __attribute__((address_space(1))) void*)gb,
          (__attribute__((address_space(3))) void*)(smem + 32768 +
                                                    (wid * 4 + q) * 1024),
          16, 0, 0);
    }
  }
  int p = 0;
  for (int kt = 0; kt < 4096; kt += GBK) {    // virtual K = 4 phases x 1024
    __syncthreads();   // stage-kt loads landed (flew during prev compute);
                       // prev compute done -> buf(1-p) free
    int kn = kt + GBK;
    if (kn < 4096) {                          // issue next stage into 1-p
      int pn = kn >> 10, kkn = kn & 1023;
      const __hip_bfloat16* Ab = PA[pn] + (size_t)(bi * 128) * DIM + kkn;
      const __hip_bfloat16* Bb = PB[pn] + (size_t)(bj * 128) * DIM + kkn;
      char* dA = smem + (1 - p) * 16384;
      char* dB = smem + 32768 + (1 - p) * 16384;
#pragma unroll
      for (int q = 0; q < 4; ++q) {
        const __hip_bfloat16* ga = Ab + (size_t)(srow + q * 8) * DIM + kcs * 8;
        const __hip_bfloat16* gb = Bb + (size_t)(srow + q * 8) * DIM + kcs * 8;
        __builtin_amdgcn_global_load_lds(
            (const __attribute__((address_space(1))) void*)ga,
            (__attribute__((address_space(3))) void*)(dA + (wid * 4 + q) * 1024),
            16, 0, 0);
        __builtin_amdgcn_global_load_lds(
            (const __attribute__((address_space(1))) void*)gb,
            (__attribute__((address_space(3))) void*)(dB + (wid * 4 + q) * 1024),
            16, 0, 0);
      }
    }
    const char* rA = smem + p * 16384;
    const char* rB = smem + 32768 + p * 16384;
#pragma unroll
    for (int kq = 0; kq < 2; ++kq) {
      int kc = kq * 4 + quad;
      bf16x8 af[4], bff[4];
#pragma unroll
      for (int r = 0; r < 4; ++r) {
        int row = wr * 64 + r * 16 + lm;
        af[r] = *(const bf16x8*)(rA + row * 128 + ((kc ^ (lm & 7)) * 16));
      }
#pragma unroll
      for (int c = 0; c < 4; ++c) {
        int row = wc * 64 + c * 16 + lm;
        bff[c] = *(const bf16x8*)(rB + row * 128 + ((kc ^ (lm & 7)) * 16));
      }
#pragma unroll
      for (int r = 0; r < 4; ++r)
#pragma unroll
        for (int c = 0; c < 4; ++c)
          acc[r][c] = __builtin_amdgcn_mfma_f32_16x16x32_bf16(
              af[r], bff[c], acc[r][c], 0, 0, 0);
    }
    p ^= 1;
  }
  // ---- epilogue: rel scaling, reference op order (unchanged)
  float rr[16], rc[4];
#pragma unroll
  for (int r = 0; r < 4; ++r)
#pragma unroll
    for (int e = 0; e < 4; ++e)
      rr[r * 4 + e] = rel[bi * 128 + wr * 64 + r * 16 + quad * 4 + e];
#pragma unroll
  for (int c = 0; c < 4; ++c) rc[c] = rel[bj * 128 + wc * 64 + c * 16 + lm];
#pragma unroll
  for (int r = 0; r < 4; ++r) {
    int grow = bi * 128 + wr * 64 + r * 16 + quad * 4;
#pragma unroll
    for (int c = 0; c < 4; ++c) {
      int gcol = bj * 128 + wc * 64 + c * 16 + lm;
#pragma unroll
      for (int e = 0; e < 4; ++e)
        ker[(size_t)(grow + e) * NTOK + gcol] =
            (acc[r][c][e] * rr[r * 4 + e]) * rc[c];
    }
  }
  if (bi != bj) {
    __syncthreads();
    float* Tw = (float*)(smem + wid * 4672);
#pragma unroll
    for (int c = 0; c < 4; ++c) {
#pragma unroll
      for (int r = 0; r < 4; ++r)
#pragma unroll
        for (int e = 0; e < 4; ++e)
          Tw[lm * 73 + r * 16 + quad * 4 + e] =
              (acc[r][c][e] * rc[c]) * rr[r * 4 + e];
      __syncthreads();
      int cc2 = lane >> 2, seg = lane & 3;
      float* dst = &ker[(size_t)(bj * 128 + wc * 64 + c * 16 + cc2) * NTOK +
                        bi * 128 + wr * 64 + seg * 16];
#pragma unroll
      for (int e = 0; e < 4; ++e)
        *(float4*)&dst[e * 4] = *(const float4*)&Tw[cc2 * 73 + seg * 16 + e * 4];
      __syncthreads();
    }
  }
}

// ---------------------------------------------------------------------------
// k_greedy: EXACT r11/r12 version (best measured: 408us; frozen).
// ---------------------------------------------------------------------------
__global__ __launch_bounds__(GT) void k_greedy(const float* __restrict__ ker,
                                               const float* __restrict__ feat,
                                               float* __restrict__ out,
                                               float* __restrict__ cisT,
                                               unsigned long long* __restrict__ slots) {
  __shared__ __align__(16) float histT[GT][132];   // [token][t], 67.6 KB
  __shared__ __align__(16) float colbuf[TOPK];
  __shared__ unsigned long long redw[GT / 64];
  __shared__ unsigned long long bwS;
  __shared__ int selj[TOPK];
  int tid = threadIdx.x;
  int lane = tid & 63, wid = tid >> 6;
  int blk = blockIdx.x;
  int n = blk * GT + tid;
  float di2s = ker[(size_t)n * NTOK + n];
#pragma unroll
  for (int t = 0; t < TOPK; t += 4)
    *(float4*)&histT[tid][t] = (float4){0.f, 0.f, 0.f, 0.f};

  for (int i = 0; i < TOPK; ++i) {
    unsigned u = __float_as_uint(di2s);
    unsigned key = (u & 0x80000000u) ? ~u : (u | 0x80000000u);
    unsigned long long pk =
        ((unsigned long long)key << 32) | (unsigned)(NTOK - 1 - n);
    for (int o = 32; o >= 1; o >>= 1) {
      unsigned long long q = __shfl_down(pk, o, 64);
      if (q > pk) pk = q;
    }
    if (lane == 0) redw[wid] = pk;
    __syncthreads();   // B1: orders redw + drains iter-(i-1) cisT stores
    if (tid == 0) {
      unsigned long long m = redw[0];
      if (redw[1] > m) m = redw[1];
      __hip_atomic_store(&slots[((size_t)i * GB + blk) * 8], m,
                         __ATOMIC_RELEASE, __HIP_MEMORY_SCOPE_AGENT);
    }
    if (wid == 0) {
      unsigned long long v = 0;
      if (lane < GB) {
        do {
          v = __hip_atomic_load(&slots[((size_t)i * GB + lane) * 8],
                                __ATOMIC_RELAXED, __HIP_MEMORY_SCOPE_AGENT);
        } while (v == 0);
      }
      unsigned long long b1 = v;
      for (int o = 32; o >= 1; o >>= 1) {
        unsigned long long q = __shfl_down(b1, o, 64);
        if (q > b1) b1 = q;
      }
      b1 = __shfl(b1, 0, 64);
      __builtin_amdgcn_fence(__ATOMIC_ACQUIRE, "agent");
      int jw = NTOK - 1 - (int)(b1 & 0xffffffffu);
      unsigned long long cu = __hip_atomic_load(
          (const unsigned long long*)(cisT + (size_t)jw * TOPK) + lane,
          __ATOMIC_RELAXED, __HIP_MEMORY_SCOPE_AGENT);
      union { unsigned long long u64; float f[2]; } cc; cc.u64 = cu;
      colbuf[lane * 2]     = cc.f[0];
      colbuf[lane * 2 + 1] = cc.f[1];
      if (lane == 0) bwS = b1;
    }
    __syncthreads();   // B2: colbuf + bwS published block-wide
    unsigned long long b1 = bwS;
    int j = NTOK - 1 - (int)(b1 & 0xffffffffu);
    unsigned kw = (unsigned)(b1 >> 32);
    unsigned du = (kw & 0x80000000u) ? (kw & 0x7fffffffu) : ~kw;
    float sd = sqrtf(__uint_as_float(du));
    if (tid == 0) selj[i] = j;
    float kj = ker[(size_t)j * NTOK + n];
    float proj = 0.f;
    for (int t = 0; t < i; t += 4) {
      float4 c4 = *(const float4*)&colbuf[t];
      float4 h4 = *(const float4*)&histT[tid][t];
      proj += c4.x * h4.x + c4.y * h4.y + c4.z * h4.z + c4.w * h4.w;
    }
    float eis = (kj - proj) / sd;
    __hip_atomic_store(&cisT[(size_t)n * TOPK + i], eis, __ATOMIC_RELAXED,
                       __HIP_MEMORY_SCOPE_AGENT);
    histT[tid][i] = eis;
    di2s -= eis * eis;
    if (n == j) di2s = NEGM;
  }
  __syncthreads();
  for (int k = blk; k < TOPK; k += GB) {
    int j = selj[k];
    const float4* src = (const float4*)(feat + (size_t)j * DIM);
    float4* dst = (float4*)(out + (size_t)k * DIM);
    dst[tid]       = src[tid];
    dst[tid + GT]  = src[tid + GT];
  }
}

// ---------------------------------------------------------------------------
// ws layout (bytes):
//   [0,262144)        slots: 128 iters x 32 blocks x 64B (zeroed each launch)
//   [262144,278528)   rel  : 4096 f32
//   [1MB, +8MB)       H    : 4096x1024 bf16
//   [1MB+8MB, +8MB)   L    : 4096x1024 bf16
//   [1MB+16MB, +2MB)  cisT : 4096x128 f32
//   [1MB+20MB, +64MB) ker  : 4096x4096 f32
// total ~85 MB
// ---------------------------------------------------------------------------
extern "C" void kernel_launch(void* const* d_in, const int* in_sizes, int n_in,
                              void* d_out, int out_size, void* d_ws, size_t ws_size,
                              hipStream_t stream) {
  const float* feat = (const float*)d_in[0];
  const float* attn = (const float*)d_in[1];
  float* out = (float*)d_out;
  char* ws = (char*)d_ws;

  unsigned long long* slots = (unsigned long long*)ws;
  float* rel = (float*)(ws + 262144);
  __hip_bfloat16* H = (__hip_bfloat16*)(ws + (1 << 20));
  __hip_bfloat16* L = (__hip_bfloat16*)(ws + (1 << 20) + (8 << 20));
  float* cisT = (float*)(ws + (1 << 20) + (16 << 20));
  float* ker  = (float*)(ws + (1 << 20) + (16 << 20) + (4 << 20));

  hipMemsetAsync(d_ws, 0, 262144, stream);
  k_prep<<<1, 1024, 0, stream>>>(attn, rel);
  k_norm<<<NTOK, 256, 0, stream>>>(feat, H, L);
  k_gemm<<<dim3(32, 32), 256, 0, stream>>>(H, L, rel, ker);
  k_greedy<<<GB, GT, 0, stream>>>(ker, feat, out, cisT, slots);
}

// Round 15
// 571.998 us; speedup vs baseline: 1.1886x; 1.0432x over previous
//
#include <hip/hip_runtime.h>
#include <hip/hip_bf16.h>
#include <stdint.h>

#define NTOK 4096
#define DIM  1024
#define TOPK 128
#define GB   32      // greedy blocks (empirical optimum)
#define GT   128     // threads per greedy block; GB*GT == NTOK
#define NEGM -1e30f

typedef __attribute__((ext_vector_type(8))) short bf16x8;
typedef __attribute__((ext_vector_type(4))) float f32x4;

// ---------------------------------------------------------------------------
// k_prep: rel[n] = ((-a[n]) - min(-a) + 1e-6) / (max(-a) - min(-a))
// ---------------------------------------------------------------------------
__global__ __launch_bounds__(1024) void k_prep(const float* __restrict__ attn,
                                               float* __restrict__ rel) {
  __shared__ float smx[16], smn[16];
  int tid = threadIdx.x;
  float mx = -3.4e38f, mn = 3.4e38f;
  for (int n = tid; n < NTOK; n += 1024) {
    float a = attn[n];
    mx = fmaxf(mx, a); mn = fminf(mn, a);
  }
  for (int o = 32; o >= 1; o >>= 1) {
    mx = fmaxf(mx, __shfl_down(mx, o, 64));
    mn = fminf(mn, __shfl_down(mn, o, 64));
  }
  if ((tid & 63) == 0) { smx[tid >> 6] = mx; smn[tid >> 6] = mn; }
  __syncthreads();
  if (tid == 0) {
    float MX = smx[0], MN = smn[0];
    for (int w = 1; w < 16; ++w) { MX = fmaxf(MX, smx[w]); MN = fminf(MN, smn[w]); }
    smx[0] = MX; smn[0] = MN;
  }
  __syncthreads();
  float amax = smx[0], amin = smn[0];
  float rmin  = -amax;
  float range = (-amin) - rmin;
  for (int n = tid; n < NTOK; n += 1024) {
    float r = -attn[n];
    rel[n] = ((r - rmin) + 1e-6f) / range;
  }
}

// ---------------------------------------------------------------------------
// k_norm: xn = x/||x||, then EXACT bf16 split: hi=bf16(xn), lo=bf16(xn-hi).
// ---------------------------------------------------------------------------
__global__ __launch_bounds__(256) void k_norm(const float* __restrict__ x,
                                              __hip_bfloat16* __restrict__ H,
                                              __hip_bfloat16* __restrict__ L) {
  __shared__ float ps[4];
  int row = blockIdx.x, tid = threadIdx.x;
  const float4* xr = (const float4*)(x + (size_t)row * DIM);
  float4 v = xr[tid];
  float s = v.x * v.x + v.y * v.y + v.z * v.z + v.w * v.w;
  for (int o = 32; o >= 1; o >>= 1) s += __shfl_down(s, o, 64);
  if ((tid & 63) == 0) ps[tid >> 6] = s;
  __syncthreads();
  if (tid == 0) ps[0] = ps[0] + ps[1] + ps[2] + ps[3];
  __syncthreads();
  float nrm = sqrtf(ps[0]);
  float xf[4] = {v.x / nrm, v.y / nrm, v.z / nrm, v.w / nrm};
  __hip_bfloat16 hh[4], ll[4];
#pragma unroll
  for (int e = 0; e < 4; ++e) {
    hh[e] = __float2bfloat16(xf[e]);
    float lof = xf[e] - __bfloat162float(hh[e]);
    ll[e] = __float2bfloat16(lof);
  }
  *(short4*)(H + (size_t)row * DIM + tid * 4) = *(short4*)hh;
  *(short4*)(L + (size_t)row * DIM + tid * 4) = *(short4*)ll;
}

// ---------------------------------------------------------------------------
// k_gemm (MFMA split-bf16, FUSED-PHASE staging): r14 read H/L tiles twice
// each (phase pointers HHLL/HLHL) -> 1.06 GB IC traffic ~= 6 TB/s = the wall.
// Now each stage stages A_H,A_L,B_H,B_L for one 32-k slice and computes all
// four products (aH*bH + aH*bL + aL*bH + aL*bL) -> every tile byte read
// ONCE (528 MB total), 2x FLOP per LDS byte, 32 stages (was 64).
// BK=32, 2x32KB ping-pong, global_load_lds w16, XOR swizzle: LDS slot s of
// row r holds global chunk s^(r&3); fragment slot quad^(lm&3) -> chunk quad.
// Accumulation ORDER changes vs r14 (same exact product terms, interleaved
// phases) -> ~1e-7 reorder, same class as the r10 switch that held absmax 0.
// ---------------------------------------------------------------------------
__global__ __launch_bounds__(256) void k_gemm(const __hip_bfloat16* __restrict__ H,
                                              const __hip_bfloat16* __restrict__ L,
                                              const float* __restrict__ rel,
                                              float* __restrict__ ker) {
  int bi = blockIdx.y, bj = blockIdx.x;
  if (bi > bj) return;
  __shared__ __align__(16) char smem[65536];  // buf p at p*32768: AH,AL,BH,BL
  int tid = threadIdx.x;
  int lane = tid & 63, wid = tid >> 6;
  int wr = wid >> 1, wc = wid & 1;
  int lm = lane & 15, quad = lane >> 4;
  int lrow = lane >> 2;                       // 0..15 within a 16-row group
  int kcf  = (lane & 3) ^ ((lane >> 2) & 3);  // global chunk to fetch (swizzle)
  const __hip_bfloat16* M[4] = {
      H + (size_t)(bi * 128) * DIM, L + (size_t)(bi * 128) * DIM,   // A_H, A_L
      H + (size_t)(bj * 128) * DIM, L + (size_t)(bj * 128) * DIM};  // B_H, B_L
  f32x4 acc[4][4];
#pragma unroll
  for (int r = 0; r < 4; ++r)
#pragma unroll
    for (int c = 0; c < 4; ++c) acc[r][c] = (f32x4){0.f, 0.f, 0.f, 0.f};

#define ISSUE_STAGE(s, pbuf)                                                   \
  {                                                                            \
    int kk = (s) * 32;                                                         \
    char* base = smem + (pbuf) * 32768;                                        \
    _Pragma("unroll")                                                          \
    for (int m = 0; m < 4; ++m) {                                              \
      _Pragma("unroll")                                                        \
      for (int q = 0; q < 2; ++q) {                                            \
        int r0 = wid * 32 + q * 16;                                            \
        const __hip_bfloat16* g =                                              \
            M[m] + (size_t)(r0 + lrow) * DIM + kk + kcf * 8;                   \
        __builtin_amdgcn_global_load_lds(                                      \
            (const __attribute__((address_space(1))) void*)g,                  \
            (__attribute__((address_space(3))) void*)(base + m * 8192 +        \
                                                      r0 * 64),                \
            16, 0, 0);                                                         \
      }                                                                        \
    }                                                                          \
  }

  ISSUE_STAGE(0, 0);
  int p = 0;
  for (int s = 0; s < 32; ++s) {              // K = 32 stages x 32
    __syncthreads();   // stage-s loads landed (flew during prev compute)
    if (s + 1 < 32) ISSUE_STAGE(s + 1, 1 - p);
    const char* b = smem + p * 32768;
    bf16x8 aH[4], aL[4], bH[4], bL[4];
#pragma unroll
    for (int r = 0; r < 4; ++r) {
      int row = wr * 64 + r * 16 + lm;        // row&3 == lm&3
      int off = row * 64 + ((quad ^ (lm & 3)) * 16);
      aH[r] = *(const bf16x8*)(b + off);
      aL[r] = *(const bf16x8*)(b + 8192 + off);
    }
#pragma unroll
    for (int c = 0; c < 4; ++c) {
      int row = wc * 64 + c * 16 + lm;
      int off = row * 64 + ((quad ^ (lm & 3)) * 16);
      bH[c] = *(const bf16x8*)(b + 16384 + off);
      bL[c] = *(const bf16x8*)(b + 24576 + off);
    }
#pragma unroll
    for (int r = 0; r < 4; ++r)
#pragma unroll
      for (int c = 0; c < 4; ++c) {
        acc[r][c] = __builtin_amdgcn_mfma_f32_16x16x32_bf16(aH[r], bH[c],
                                                            acc[r][c], 0, 0, 0);
        acc[r][c] = __builtin_amdgcn_mfma_f32_16x16x32_bf16(aH[r], bL[c],
                                                            acc[r][c], 0, 0, 0);
        acc[r][c] = __builtin_amdgcn_mfma_f32_16x16x32_bf16(aL[r], bH[c],
                                                            acc[r][c], 0, 0, 0);
        acc[r][c] = __builtin_amdgcn_mfma_f32_16x16x32_bf16(aL[r], bL[c],
                                                            acc[r][c], 0, 0, 0);
      }
    p ^= 1;
  }
#undef ISSUE_STAGE
  // ---- epilogue: rel scaling, reference op order (unchanged from r14)
  float rr[16], rc[4];
#pragma unroll
  for (int r = 0; r < 4; ++r)
#pragma unroll
    for (int e = 0; e < 4; ++e)
      rr[r * 4 + e] = rel[bi * 128 + wr * 64 + r * 16 + quad * 4 + e];
#pragma unroll
  for (int c = 0; c < 4; ++c) rc[c] = rel[bj * 128 + wc * 64 + c * 16 + lm];
#pragma unroll
  for (int r = 0; r < 4; ++r) {
    int grow = bi * 128 + wr * 64 + r * 16 + quad * 4;
#pragma unroll
    for (int c = 0; c < 4; ++c) {
      int gcol = bj * 128 + wc * 64 + c * 16 + lm;
#pragma unroll
      for (int e = 0; e < 4; ++e)
        ker[(size_t)(grow + e) * NTOK + gcol] =
            (acc[r][c][e] * rr[r * 4 + e]) * rc[c];
    }
  }
  if (bi != bj) {
    __syncthreads();
    float* Tw = (float*)(smem + wid * 4672);
#pragma unroll
    for (int c = 0; c < 4; ++c) {
#pragma unroll
      for (int r = 0; r < 4; ++r)
#pragma unroll
        for (int e = 0; e < 4; ++e)
          Tw[lm * 73 + r * 16 + quad * 4 + e] =
              (acc[r][c][e] * rc[c]) * rr[r * 4 + e];
      __syncthreads();
      int cc2 = lane >> 2, seg = lane & 3;
      float* dst = &ker[(size_t)(bj * 128 + wc * 64 + c * 16 + cc2) * NTOK +
                        bi * 128 + wr * 64 + seg * 16];
#pragma unroll
      for (int e = 0; e < 4; ++e)
        *(float4*)&dst[e * 4] = *(const float4*)&Tw[cc2 * 73 + seg * 16 + e * 4];
      __syncthreads();
    }
  }
}

// ---------------------------------------------------------------------------
// k_greedy: EXACT r11/r12/r14 version (best measured ~400us; frozen).
// ---------------------------------------------------------------------------
__global__ __launch_bounds__(GT) void k_greedy(const float* __restrict__ ker,
                                               const float* __restrict__ feat,
                                               float* __restrict__ out,
                                               float* __restrict__ cisT,
                                               unsigned long long* __restrict__ slots) {
  __shared__ __align__(16) float histT[GT][132];   // [token][t], 67.6 KB
  __shared__ __align__(16) float colbuf[TOPK];
  __shared__ unsigned long long redw[GT / 64];
  __shared__ unsigned long long bwS;
  __shared__ int selj[TOPK];
  int tid = threadIdx.x;
  int lane = tid & 63, wid = tid >> 6;
  int blk = blockIdx.x;
  int n = blk * GT + tid;
  float di2s = ker[(size_t)n * NTOK + n];
#pragma unroll
  for (int t = 0; t < TOPK; t += 4)
    *(float4*)&histT[tid][t] = (float4){0.f, 0.f, 0.f, 0.f};

  for (int i = 0; i < TOPK; ++i) {
    unsigned u = __float_as_uint(di2s);
    unsigned key = (u & 0x80000000u) ? ~u : (u | 0x80000000u);
    unsigned long long pk =
        ((unsigned long long)key << 32) | (unsigned)(NTOK - 1 - n);
    for (int o = 32; o >= 1; o >>= 1) {
      unsigned long long q = __shfl_down(pk, o, 64);
      if (q > pk) pk = q;
    }
    if (lane == 0) redw[wid] = pk;
    __syncthreads();   // B1: orders redw + drains iter-(i-1) cisT stores
    if (tid == 0) {
      unsigned long long m = redw[0];
      if (redw[1] > m) m = redw[1];
      __hip_atomic_store(&slots[((size_t)i * GB + blk) * 8], m,
                         __ATOMIC_RELEASE, __HIP_MEMORY_SCOPE_AGENT);
    }
    if (wid == 0) {
      unsigned long long v = 0;
      if (lane < GB) {
        do {
          v = __hip_atomic_load(&slots[((size_t)i * GB + lane) * 8],
                                __ATOMIC_RELAXED, __HIP_MEMORY_SCOPE_AGENT);
        } while (v == 0);
      }
      unsigned long long b1 = v;
      for (int o = 32; o >= 1; o >>= 1) {
        unsigned long long q = __shfl_down(b1, o, 64);
        if (q > b1) b1 = q;
      }
      b1 = __shfl(b1, 0, 64);
      __builtin_amdgcn_fence(__ATOMIC_ACQUIRE, "agent");
      int jw = NTOK - 1 - (int)(b1 & 0xffffffffu);
      unsigned long long cu = __hip_atomic_load(
          (const unsigned long long*)(cisT + (size_t)jw * TOPK) + lane,
          __ATOMIC_RELAXED, __HIP_MEMORY_SCOPE_AGENT);
      union { unsigned long long u64; float f[2]; } cc; cc.u64 = cu;
      colbuf[lane * 2]     = cc.f[0];
      colbuf[lane * 2 + 1] = cc.f[1];
      if (lane == 0) bwS = b1;
    }
    __syncthreads();   // B2: colbuf + bwS published block-wide
    unsigned long long b1 = bwS;
    int j = NTOK - 1 - (int)(b1 & 0xffffffffu);
    unsigned kw = (unsigned)(b1 >> 32);
    unsigned du = (kw & 0x80000000u) ? (kw & 0x7fffffffu) : ~kw;
    float sd = sqrtf(__uint_as_float(du));
    if (tid == 0) selj[i] = j;
    float kj = ker[(size_t)j * NTOK + n];
    float proj = 0.f;
    for (int t = 0; t < i; t += 4) {
      float4 c4 = *(const float4*)&colbuf[t];
      float4 h4 = *(const float4*)&histT[tid][t];
      proj += c4.x * h4.x + c4.y * h4.y + c4.z * h4.z + c4.w * h4.w;
    }
    float eis = (kj - proj) / sd;
    __hip_atomic_store(&cisT[(size_t)n * TOPK + i], eis, __ATOMIC_RELAXED,
                       __HIP_MEMORY_SCOPE_AGENT);
    histT[tid][i] = eis;
    di2s -= eis * eis;
    if (n == j) di2s = NEGM;
  }
  __syncthreads();
  for (int k = blk; k < TOPK; k += GB) {
    int j = selj[k];
    const float4* src = (const float4*)(feat + (size_t)j * DIM);
    float4* dst = (float4*)(out + (size_t)k * DIM);
    dst[tid]       = src[tid];
    dst[tid + GT]  = src[tid + GT];
  }
}

// ---------------------------------------------------------------------------
// ws layout (bytes):
//   [0,262144)        slots: 128 iters x 32 blocks x 64B (zeroed each launch)
//   [262144,278528)   rel  : 4096 f32
//   [1MB, +8MB)       H    : 4096x1024 bf16
//   [1MB+8MB, +8MB)   L    : 4096x1024 bf16
//   [1MB+16MB, +2MB)  cisT : 4096x128 f32
//   [1MB+20MB, +64MB) ker  : 4096x4096 f32
// total ~85 MB
// ---------------------------------------------------------------------------
extern "C" void kernel_launch(void* const* d_in, const int* in_sizes, int n_in,
                              void* d_out, int out_size, void* d_ws, size_t ws_size,
                              hipStream_t stream) {
  const float* feat = (const float*)d_in[0];
  const float* attn = (const float*)d_in[1];
  float* out = (float*)d_out;
  char* ws = (char*)d_ws;

  unsigned long long* slots = (unsigned long long*)ws;
  float* rel = (float*)(ws + 262144);
  __hip_bfloat16* H = (__hip_bfloat16*)(ws + (1 << 20));
  __hip_bfloat16* L = (__hip_bfloat16*)(ws + (1 << 20) + (8 << 20));
  float* cisT = (float*)(ws + (1 << 20) + (16 << 20));
  float* ker  = (float*)(ws + (1 << 20) + (16 << 20) + (4 << 20));

  hipMemsetAsync(d_ws, 0, 262144, stream);
  k_prep<<<1, 1024, 0, stream>>>(attn, rel);
  k_norm<<<NTOK, 256, 0, stream>>>(feat, H, L);
  k_gemm<<<dim3(32, 32), 256, 0, stream>>>(H, L, rel, ker);
  k_greedy<<<GB, GT, 0, stream>>>(ker, feat, out, cisT, slots);
}